// Round 1
// baseline (578.104 us; speedup 1.0000x reference)
//
#include <hip/hip_runtime.h>
#include <hip/hip_bf16.h>
#include <cstdint>
#include <cstddef>

// Problem constants
// B=2, S=2048, D=1024, H=16, DH=64, FF=4096, M=B*S=4096

typedef short bf16x8 __attribute__((ext_vector_type(8)));
typedef float f32x4 __attribute__((ext_vector_type(4)));

#define DEV static __device__ __forceinline__

DEV unsigned short f2bf(float f) {
  union { float fv; unsigned u; } a; a.fv = f;
  unsigned r = a.u + 0x7FFFu + ((a.u >> 16) & 1u);
  return (unsigned short)(r >> 16);
}

DEV void gload_lds16(const void* g, void* l) {
  __builtin_amdgcn_global_load_lds(
      (const __attribute__((address_space(1))) unsigned int*)g,
      (__attribute__((address_space(3))) unsigned int*)l,
      16, 0, 0);
}

// ---------------- transpose f32 [batch][R][C] -> bf16 [batch][C][R] ----------------
__global__ __launch_bounds__(256) void k_transpose(const float* __restrict__ in,
                                                   unsigned short* __restrict__ out,
                                                   int R, int C,
                                                   long inBatchStride, long outBatchStride) {
  __shared__ float tile[32][33];
  long batch = blockIdx.z;
  int c0 = blockIdx.x * 32;
  int r0 = blockIdx.y * 32;
  const float* src = in + batch * inBatchStride;
  unsigned short* dst = out + batch * outBatchStride;
  int tx = threadIdx.x, ty = threadIdx.y;  // (32, 8)
  #pragma unroll
  for (int i = ty; i < 32; i += 8)
    tile[i][tx] = src[(long)(r0 + i) * C + (c0 + tx)];
  __syncthreads();
  #pragma unroll
  for (int i = ty; i < 32; i += 8)
    dst[(long)(c0 + i) * R + (r0 + tx)] = f2bf(tile[tx][i]);
}

// ---------------- concat q/k/v biases into one [3072] vector ----------------
__global__ void k_concat_bias(const float* __restrict__ bq, const float* __restrict__ bk,
                              const float* __restrict__ bv, float* __restrict__ out) {
  int i = blockIdx.x * 256 + threadIdx.x;
  if (i < 1024) out[i] = bq[i];
  else if (i < 2048) out[i] = bk[i - 1024];
  else if (i < 3072) out[i] = bv[i - 2048];
}

// ---------------- LayerNorm f32 [4096][1024] -> bf16 ----------------
__global__ __launch_bounds__(256) void k_ln_bf16(const float* __restrict__ x,
                                                 const float* __restrict__ g,
                                                 const float* __restrict__ b,
                                                 unsigned short* __restrict__ out) {
  int row = blockIdx.x;
  const float* xr = x + (size_t)row * 1024;
  int t = threadIdx.x;
  float4 v = *(const float4*)(xr + t * 4);
  float s = v.x + v.y + v.z + v.w;
  float s2 = v.x * v.x + v.y * v.y + v.z * v.z + v.w * v.w;
  for (int off = 32; off > 0; off >>= 1) {
    s  += __shfl_down(s,  off, 64);
    s2 += __shfl_down(s2, off, 64);
  }
  __shared__ float ws1[4], ws2[4];
  __shared__ float mu_s, rs_s;
  int wid = t >> 6, lane = t & 63;
  if (lane == 0) { ws1[wid] = s; ws2[wid] = s2; }
  __syncthreads();
  if (t == 0) {
    float S1 = ws1[0] + ws1[1] + ws1[2] + ws1[3];
    float S2 = ws2[0] + ws2[1] + ws2[2] + ws2[3];
    float mu = S1 * (1.0f / 1024.0f);
    float var = S2 * (1.0f / 1024.0f) - mu * mu;
    mu_s = mu;
    rs_s = rsqrtf(var + 1e-5f);
  }
  __syncthreads();
  float mu = mu_s, rs = rs_s;
  float4 gv = *(const float4*)(g + t * 4);
  float4 bv = *(const float4*)(b + t * 4);
  ushort4 o;
  o.x = f2bf((v.x - mu) * rs * gv.x + bv.x);
  o.y = f2bf((v.y - mu) * rs * gv.y + bv.y);
  o.z = f2bf((v.z - mu) * rs * gv.z + bv.z);
  o.w = f2bf((v.w - mu) * rs * gv.w + bv.w);
  *(ushort4*)(out + (size_t)row * 1024 + t * 4) = o;
}

// ---------------- GEMM: C[M][N] = A[M][K] * Bt[N][K]^T + bias, epilogues ----------------
// EPI 0: store bf16; EPI 1: gelu(exact) + store bf16; EPI 2: f32 Cout += val
template <int EPI>
__global__ __launch_bounds__(256) void k_gemm_bt(const unsigned short* __restrict__ A,
                                                 const unsigned short* __restrict__ Bt,
                                                 const float* __restrict__ bias,
                                                 void* __restrict__ Cout,
                                                 int M, int N, int K) {
  __shared__ __align__(16) unsigned short As[128 * 64];
  __shared__ __align__(16) unsigned short Bs[128 * 64];
  int tid = threadIdx.x;
  int col0 = blockIdx.x * 128;
  int row0 = blockIdx.y * 128;
  int wid = tid >> 6, lane = tid & 63;
  int wr = wid >> 1, wc = wid & 1;
  int lrow = lane & 15;
  int kgrp = (lane >> 4) * 8;
  int srow = tid >> 3;        // 0..31
  int scol = (tid & 7) * 8;   // 0..56

  f32x4 acc[4][4];
  f32x4 zero = {0.f, 0.f, 0.f, 0.f};
  #pragma unroll
  for (int m = 0; m < 4; ++m)
    #pragma unroll
    for (int n = 0; n < 4; ++n) acc[m][n] = zero;

  for (int k0 = 0; k0 < K; k0 += 64) {
    #pragma unroll
    for (int i = 0; i < 4; ++i) {
      int r = i * 32 + srow;
      gload_lds16(A  + (size_t)(row0 + r) * K + k0 + scol, (char*)As + i * 4096 + tid * 16);
      gload_lds16(Bt + (size_t)(col0 + r) * K + k0 + scol, (char*)Bs + i * 4096 + tid * 16);
    }
    __syncthreads();
    bf16x8 af[4][2], bf[4][2];
    #pragma unroll
    for (int m = 0; m < 4; ++m)
      #pragma unroll
      for (int kk = 0; kk < 2; ++kk)
        af[m][kk] = *(const bf16x8*)(As + (wr * 64 + m * 16 + lrow) * 64 + kk * 32 + kgrp);
    #pragma unroll
    for (int n = 0; n < 4; ++n)
      #pragma unroll
      for (int kk = 0; kk < 2; ++kk)
        bf[n][kk] = *(const bf16x8*)(Bs + (wc * 64 + n * 16 + lrow) * 64 + kk * 32 + kgrp);
    #pragma unroll
    for (int m = 0; m < 4; ++m)
      #pragma unroll
      for (int n = 0; n < 4; ++n)
        #pragma unroll
        for (int kk = 0; kk < 2; ++kk)
          acc[m][n] = __builtin_amdgcn_mfma_f32_16x16x32_bf16(af[m][kk], bf[n][kk], acc[m][n], 0, 0, 0);
    __syncthreads();
  }

  int rbase = row0 + wr * 64 + (lane >> 4) * 4;
  int cbase = col0 + wc * 64 + (lane & 15);
  #pragma unroll
  for (int m = 0; m < 4; ++m) {
    #pragma unroll
    for (int n = 0; n < 4; ++n) {
      int col = cbase + n * 16;
      float bia = bias[col];
      #pragma unroll
      for (int j = 0; j < 4; ++j) {
        int row = rbase + m * 16 + j;
        float v = acc[m][n][j] + bia;
        if constexpr (EPI == 0) {
          ((unsigned short*)Cout)[(size_t)row * N + col] = f2bf(v);
        } else if constexpr (EPI == 1) {
          float gel = 0.5f * v * (1.0f + erff(v * 0.70710678118f));
          ((unsigned short*)Cout)[(size_t)row * N + col] = f2bf(gel);
        } else {
          float* o = (float*)Cout + (size_t)row * N + col;
          *o += v;
        }
      }
    }
  }
}

// ---------------- fused causal flash attention + residual ----------------
// qkv: bf16 [4096][3072] (Q|K|V per head concat); x: f32 [4096][1024]; out = x + attn
__global__ __launch_bounds__(256) void k_flash_attn(const unsigned short* __restrict__ qkv,
                                                    const float* __restrict__ x,
                                                    float* __restrict__ out) {
  int blk = blockIdx.x;
  int qb = blk & 31;       // q-block (64 rows)
  int bh = blk >> 5;       // b*16+h
  int b = bh >> 4, h = bh & 15;
  const int LDQ = 3072;
  int tb = b * 2048;
  int qcol = h * 64, kcol = 1024 + h * 64, vcol = 2048 + h * 64;
  int q0 = qb * 64;
  int tid = threadIdx.x, wid = tid >> 6, lane = tid & 63;
  int lrow = lane & 15;
  int kgrp = (lane >> 4) * 8;
  int srow = tid >> 3;
  int scol = (tid & 7) * 8;

  __shared__ __align__(16) unsigned short Ks[64 * 64];
  __shared__ __align__(16) unsigned short Vt[64 * 64];
  __shared__ __align__(16) unsigned short Pl[4][16 * 64];

  // Q fragments: wave owns rows q0 + wid*16 .. +15
  bf16x8 aq[2];
  #pragma unroll
  for (int kk = 0; kk < 2; ++kk)
    aq[kk] = *(const bf16x8*)(qkv + (size_t)(tb + q0 + wid * 16 + lrow) * LDQ + qcol + kk * 32 + kgrp);

  f32x4 oacc[4];
  f32x4 zero = {0.f, 0.f, 0.f, 0.f};
  #pragma unroll
  for (int e = 0; e < 4; ++e) oacc[e] = zero;
  float mrun[4], lrun[4];
  #pragma unroll
  for (int r = 0; r < 4; ++r) { mrun[r] = -1e30f; lrun[r] = 0.0f; }

  for (int j = 0; j <= qb; ++j) {
    __syncthreads();  // previous iteration's LDS reads done before overwrite
    // stage K tile [64][64]
    #pragma unroll
    for (int i = 0; i < 2; ++i)
      gload_lds16(qkv + (size_t)(tb + j * 64 + i * 32 + srow) * LDQ + kcol + scol,
                  (char*)Ks + i * 4096 + tid * 16);
    // stage V^T tile: Vt[e][t] = V[t][e]
    #pragma unroll
    for (int i = 0; i < 2; ++i) {
      int chunk = i * 256 + tid;
      int t = chunk >> 3;
      int e0 = (chunk & 7) * 8;
      bf16x8 vv = *(const bf16x8*)(qkv + (size_t)(tb + j * 64 + t) * LDQ + vcol + e0);
      #pragma unroll
      for (int jj = 0; jj < 8; ++jj)
        Vt[(e0 + jj) * 64 + t] = (unsigned short)vv[jj];
    }
    __syncthreads();

    // S = Q K^T  (16 rows x 64 cols per wave)
    f32x4 sacc[4];
    #pragma unroll
    for (int n = 0; n < 4; ++n) sacc[n] = zero;
    #pragma unroll
    for (int n = 0; n < 4; ++n)
      #pragma unroll
      for (int kk = 0; kk < 2; ++kk) {
        bf16x8 bk = *(const bf16x8*)(Ks + (n * 16 + lrow) * 64 + kk * 32 + kgrp);
        sacc[n] = __builtin_amdgcn_mfma_f32_16x16x32_bf16(aq[kk], bk, sacc[n], 0, 0, 0);
      }

    // online softmax
    bool diag = (j == qb);
    float pv[4][4];
    #pragma unroll
    for (int r = 0; r < 4; ++r) {
      int sg = q0 + wid * 16 + (lane >> 4) * 4 + r;  // global query index
      float mx = -1e30f;
      #pragma unroll
      for (int n = 0; n < 4; ++n) {
        float sv = sacc[n][r] * 0.125f;
        int tg = j * 64 + n * 16 + (lane & 15);      // global key index
        if (diag && tg > sg) sv = -1e30f;
        pv[r][n] = sv;
        mx = fmaxf(mx, sv);
      }
      #pragma unroll
      for (int off = 1; off < 16; off <<= 1) mx = fmaxf(mx, __shfl_xor(mx, off, 64));
      float mnew = fmaxf(mrun[r], mx);
      float esc = __expf(mrun[r] - mnew);
      float rsum = 0.f;
      #pragma unroll
      for (int n = 0; n < 4; ++n) {
        float p = __expf(pv[r][n] - mnew);
        pv[r][n] = p;
        rsum += p;
      }
      #pragma unroll
      for (int off = 1; off < 16; off <<= 1) rsum += __shfl_xor(rsum, off, 64);
      lrun[r] = lrun[r] * esc + rsum;
      mrun[r] = mnew;
      #pragma unroll
      for (int e = 0; e < 4; ++e) oacc[e][r] *= esc;
      #pragma unroll
      for (int n = 0; n < 4; ++n)
        Pl[wid][((lane >> 4) * 4 + r) * 64 + n * 16 + (lane & 15)] = f2bf(pv[r][n]);
    }
    __syncthreads();  // P visible (and Vt already staged)

    // O += P V
    #pragma unroll
    for (int kk = 0; kk < 2; ++kk) {
      bf16x8 ap = *(const bf16x8*)(&Pl[wid][0] + lrow * 64 + kk * 32 + kgrp);
      #pragma unroll
      for (int e = 0; e < 4; ++e) {
        bf16x8 bv = *(const bf16x8*)(Vt + (e * 16 + lrow) * 64 + kk * 32 + kgrp);
        oacc[e] = __builtin_amdgcn_mfma_f32_16x16x32_bf16(ap, bv, oacc[e], 0, 0, 0);
      }
    }
  }

  // epilogue: out = x + O / l
  #pragma unroll
  for (int r = 0; r < 4; ++r) {
    float inv = 1.0f / lrun[r];
    int row = tb + q0 + wid * 16 + (lane >> 4) * 4 + r;
    #pragma unroll
    for (int e = 0; e < 4; ++e) {
      size_t idx = (size_t)row * 1024 + h * 64 + e * 16 + (lane & 15);
      out[idx] = x[idx] + oacc[e][r] * inv;
    }
  }
}

// ---------------- launch ----------------
extern "C" void kernel_launch(void* const* d_in, const int* in_sizes, int n_in,
                              void* d_out, int out_size, void* d_ws, size_t ws_size,
                              hipStream_t stream) {
  (void)in_sizes; (void)n_in; (void)out_size; (void)ws_size;
  const float* x    = (const float*)d_in[0];
  const float* Wq   = (const float*)d_in[1];
  const float* bq   = (const float*)d_in[2];
  const float* Wk   = (const float*)d_in[3];
  const float* bk   = (const float*)d_in[4];
  const float* Wv   = (const float*)d_in[5];
  const float* bv   = (const float*)d_in[6];
  const float* ln1g = (const float*)d_in[7];
  const float* ln1b = (const float*)d_in[8];
  const float* ln2g = (const float*)d_in[9];
  const float* ln2b = (const float*)d_in[10];
  const float* W1   = (const float*)d_in[11];
  const float* b1   = (const float*)d_in[12];
  const float* W2   = (const float*)d_in[13];
  const float* b2   = (const float*)d_in[14];
  float* out = (float*)d_out;
  char* ws = (char*)d_ws;

  unsigned short* h1    = (unsigned short*)(ws + 0);          // 8 MiB  [4096][1024] bf16
  unsigned short* wqkvT = (unsigned short*)(ws + 8388608);    // 6 MiB  [3072][1024] bf16
  unsigned short* w1T   = (unsigned short*)(ws + 14680064);   // 8 MiB  [4096][1024] bf16
  unsigned short* w2T   = (unsigned short*)(ws + 23068672);   // 8 MiB  [1024][4096] bf16
  float*          bqkv  = (float*)(ws + 31457280);            // 12 KiB [3072] f32
  unsigned short* qkv   = (unsigned short*)(ws + 33554432);   // 24 MiB [4096][3072] bf16
  unsigned short* fbuf  = (unsigned short*)(ws + 33554432);   // 32 MiB [4096][4096] bf16 (overlaps qkv; qkv dead by then)

  dim3 tb(32, 8);
  // Wq/Wk/Wv: [16][1024][64] -> [16][64][1024] concat into wqkvT
  k_transpose<<<dim3(2, 32, 16), tb, 0, stream>>>(Wq, wqkvT,               1024, 64, 1024L * 64, 64L * 1024);
  k_transpose<<<dim3(2, 32, 16), tb, 0, stream>>>(Wk, wqkvT + 1024 * 1024, 1024, 64, 1024L * 64, 64L * 1024);
  k_transpose<<<dim3(2, 32, 16), tb, 0, stream>>>(Wv, wqkvT + 2048 * 1024, 1024, 64, 1024L * 64, 64L * 1024);
  // W1: [1024][4096] -> w1T [4096][1024]
  k_transpose<<<dim3(128, 32, 1), tb, 0, stream>>>(W1, w1T, 1024, 4096, 0, 0);
  // W2: [4096][1024] -> w2T [1024][4096]
  k_transpose<<<dim3(32, 128, 1), tb, 0, stream>>>(W2, w2T, 4096, 1024, 0, 0);
  k_concat_bias<<<12, 256, 0, stream>>>(bq, bk, bv, bqkv);

  // LN1
  k_ln_bf16<<<4096, 256, 0, stream>>>(x, ln1g, ln1b, h1);
  // QKV projection: [4096][1024] x [1024][3072] -> qkv bf16
  k_gemm_bt<0><<<dim3(24, 32), 256, 0, stream>>>(h1, wqkvT, bqkv, qkv, 4096, 3072, 1024);
  // attention + residual: out = x + attn
  k_flash_attn<<<1024, 256, 0, stream>>>(qkv, x, out);
  // LN2 (reads out)
  k_ln_bf16<<<4096, 256, 0, stream>>>(out, ln2g, ln2b, h1);
  // FFN1 + GELU: [4096][1024] x [1024][4096] -> fbuf bf16
  k_gemm_bt<1><<<dim3(32, 32), 256, 0, stream>>>(h1, w1T, b1, fbuf, 4096, 4096, 1024);
  // FFN2: [4096][4096] x [4096][1024] += out
  k_gemm_bt<2><<<dim3(8, 32), 256, 0, stream>>>(fbuf, w2T, b2, out, 4096, 1024, 4096);
}

// Round 2
// 450.885 us; speedup vs baseline: 1.2822x; 1.2822x over previous
//
#include <hip/hip_runtime.h>
#include <hip/hip_bf16.h>
#include <cstdint>
#include <cstddef>

// Problem constants
// B=2, S=2048, D=1024, H=16, DH=64, FF=4096, M=B*S=4096

typedef short bf16x8 __attribute__((ext_vector_type(8)));
typedef float f32x4 __attribute__((ext_vector_type(4)));

#define DEV static __device__ __forceinline__

DEV unsigned short f2bf(float f) {
  union { float fv; unsigned u; } a; a.fv = f;
  unsigned r = a.u + 0x7FFFu + ((a.u >> 16) & 1u);
  return (unsigned short)(r >> 16);
}

DEV void gload_lds16(const void* g, void* l) {
  __builtin_amdgcn_global_load_lds(
      (const __attribute__((address_space(1))) unsigned int*)g,
      (__attribute__((address_space(3))) unsigned int*)l,
      16, 0, 0);
}

// ---------------- transpose f32 [batch][R][C] -> bf16 [batch][C][R] ----------------
__global__ __launch_bounds__(256) void k_transpose(const float* __restrict__ in,
                                                   unsigned short* __restrict__ out,
                                                   int R, int C,
                                                   long inBatchStride, long outBatchStride) {
  __shared__ float tile[32][33];
  long batch = blockIdx.z;
  int c0 = blockIdx.x * 32;
  int r0 = blockIdx.y * 32;
  const float* src = in + batch * inBatchStride;
  unsigned short* dst = out + batch * outBatchStride;
  int tx = threadIdx.x, ty = threadIdx.y;  // (32, 8)
  #pragma unroll
  for (int i = ty; i < 32; i += 8)
    tile[i][tx] = src[(long)(r0 + i) * C + (c0 + tx)];
  __syncthreads();
  #pragma unroll
  for (int i = ty; i < 32; i += 8)
    dst[(long)(c0 + i) * R + (r0 + tx)] = f2bf(tile[tx][i]);
}

// ---------------- concat q/k/v biases into one [3072] vector ----------------
__global__ void k_concat_bias(const float* __restrict__ bq, const float* __restrict__ bk,
                              const float* __restrict__ bv, float* __restrict__ out) {
  int i = blockIdx.x * 256 + threadIdx.x;
  if (i < 1024) out[i] = bq[i];
  else if (i < 2048) out[i] = bk[i - 1024];
  else if (i < 3072) out[i] = bv[i - 2048];
}

// ---------------- LayerNorm f32 [4096][1024] -> bf16 ----------------
__global__ __launch_bounds__(256) void k_ln_bf16(const float* __restrict__ x,
                                                 const float* __restrict__ g,
                                                 const float* __restrict__ b,
                                                 unsigned short* __restrict__ out) {
  int row = blockIdx.x;
  const float* xr = x + (size_t)row * 1024;
  int t = threadIdx.x;
  float4 v = *(const float4*)(xr + t * 4);
  float s = v.x + v.y + v.z + v.w;
  float s2 = v.x * v.x + v.y * v.y + v.z * v.z + v.w * v.w;
  for (int off = 32; off > 0; off >>= 1) {
    s  += __shfl_down(s,  off, 64);
    s2 += __shfl_down(s2, off, 64);
  }
  __shared__ float ws1[4], ws2[4];
  __shared__ float mu_s, rs_s;
  int wid = t >> 6, lane = t & 63;
  if (lane == 0) { ws1[wid] = s; ws2[wid] = s2; }
  __syncthreads();
  if (t == 0) {
    float S1 = ws1[0] + ws1[1] + ws1[2] + ws1[3];
    float S2 = ws2[0] + ws2[1] + ws2[2] + ws2[3];
    float mu = S1 * (1.0f / 1024.0f);
    float var = S2 * (1.0f / 1024.0f) - mu * mu;
    mu_s = mu;
    rs_s = rsqrtf(var + 1e-5f);
  }
  __syncthreads();
  float mu = mu_s, rs = rs_s;
  float4 gv = *(const float4*)(g + t * 4);
  float4 bv = *(const float4*)(b + t * 4);
  ushort4 o;
  o.x = f2bf((v.x - mu) * rs * gv.x + bv.x);
  o.y = f2bf((v.y - mu) * rs * gv.y + bv.y);
  o.z = f2bf((v.z - mu) * rs * gv.z + bv.z);
  o.w = f2bf((v.w - mu) * rs * gv.w + bv.w);
  *(ushort4*)(out + (size_t)row * 1024 + t * 4) = o;
}

// ---------------- GEMM: C[M][N] = A[M][K] * Bt[N][K]^T + bias, epilogues ----------------
// EPI 0: store bf16; EPI 1: gelu(exact) + store bf16; EPI 2: f32 Cout += val
template <int EPI>
__global__ __launch_bounds__(256) void k_gemm_bt(const unsigned short* __restrict__ A,
                                                 const unsigned short* __restrict__ Bt,
                                                 const float* __restrict__ bias,
                                                 void* __restrict__ Cout,
                                                 int M, int N, int K) {
  __shared__ __align__(16) unsigned short As[128 * 64];
  __shared__ __align__(16) unsigned short Bs[128 * 64];
  int tid = threadIdx.x;
  int col0 = blockIdx.x * 128;
  int row0 = blockIdx.y * 128;
  int wid = tid >> 6, lane = tid & 63;
  int wr = wid >> 1, wc = wid & 1;
  int lrow = lane & 15;
  int kgrp = (lane >> 4) * 8;
  int srow = tid >> 3;        // 0..31
  int scol = (tid & 7) * 8;   // 0..56

  f32x4 acc[4][4];
  f32x4 zero = {0.f, 0.f, 0.f, 0.f};
  #pragma unroll
  for (int m = 0; m < 4; ++m)
    #pragma unroll
    for (int n = 0; n < 4; ++n) acc[m][n] = zero;

  for (int k0 = 0; k0 < K; k0 += 64) {
    #pragma unroll
    for (int i = 0; i < 4; ++i) {
      int r = i * 32 + srow;
      gload_lds16(A  + (size_t)(row0 + r) * K + k0 + scol, (char*)As + i * 4096 + tid * 16);
      gload_lds16(Bt + (size_t)(col0 + r) * K + k0 + scol, (char*)Bs + i * 4096 + tid * 16);
    }
    __syncthreads();
    bf16x8 af[4][2], bf[4][2];
    #pragma unroll
    for (int m = 0; m < 4; ++m)
      #pragma unroll
      for (int kk = 0; kk < 2; ++kk)
        af[m][kk] = *(const bf16x8*)(As + (wr * 64 + m * 16 + lrow) * 64 + kk * 32 + kgrp);
    #pragma unroll
    for (int n = 0; n < 4; ++n)
      #pragma unroll
      for (int kk = 0; kk < 2; ++kk)
        bf[n][kk] = *(const bf16x8*)(Bs + (wc * 64 + n * 16 + lrow) * 64 + kk * 32 + kgrp);
    #pragma unroll
    for (int m = 0; m < 4; ++m)
      #pragma unroll
      for (int n = 0; n < 4; ++n)
        #pragma unroll
        for (int kk = 0; kk < 2; ++kk)
          acc[m][n] = __builtin_amdgcn_mfma_f32_16x16x32_bf16(af[m][kk], bf[n][kk], acc[m][n], 0, 0, 0);
    __syncthreads();
  }

  int rbase = row0 + wr * 64 + (lane >> 4) * 4;
  int cbase = col0 + wc * 64 + (lane & 15);
  #pragma unroll
  for (int m = 0; m < 4; ++m) {
    #pragma unroll
    for (int n = 0; n < 4; ++n) {
      int col = cbase + n * 16;
      float bia = bias[col];
      #pragma unroll
      for (int j = 0; j < 4; ++j) {
        int row = rbase + m * 16 + j;
        float v = acc[m][n][j] + bia;
        if constexpr (EPI == 0) {
          ((unsigned short*)Cout)[(size_t)row * N + col] = f2bf(v);
        } else if constexpr (EPI == 1) {
          float gel = 0.5f * v * (1.0f + erff(v * 0.70710678118f));
          ((unsigned short*)Cout)[(size_t)row * N + col] = f2bf(gel);
        } else {
          float* o = (float*)Cout + (size_t)row * N + col;
          *o += v;
        }
      }
    }
  }
}

// ---------------- fused causal flash attention + residual ----------------
// qkv: bf16 [4096][3072] (Q|K|V per head concat); x: f32 [4096][1024]; out = x + attn
// Grid: 512 blocks = 32 (b*h) x 16 q-tile pairs (p, 31-p) -> 33 KV-tile iters each.
// LDS layouts XOR-chunk-swizzled (16B chunks, row stride 128B):
//   Ks[buf][row t][chunk c]: holds global d-chunk c ^ (t&7)   (staged via gload_lds w/ pre-swizzled src)
//   Vt[buf][row e][chunk c]: holds global t-chunk c ^ (e&7) ^ (e>>3)
//   Pl[wave][row q][chunk c]: holds t-chunk c ^ (q&7)
__global__ __launch_bounds__(256) void k_flash_attn(const unsigned short* __restrict__ qkv,
                                                    const float* __restrict__ x,
                                                    float* __restrict__ out) {
  int blk = blockIdx.x;
  int pairIdx = blk & 15;
  int bh = blk >> 4;
  int b = bh >> 4, h = bh & 15;
  const int LDQ = 3072;
  int tb = b * 2048;
  int qcol = h * 64, kcol = 1024 + h * 64, vcol = 2048 + h * 64;
  int tid = threadIdx.x, wid = tid >> 6, lane = tid & 63;
  int lrow = lane & 15;
  int g = lane >> 4;
  int kgrp = g * 8;

  __shared__ __align__(16) unsigned short Ks[2][64 * 64];
  __shared__ __align__(16) unsigned short Vt[2][64 * 64];
  __shared__ __align__(16) unsigned short Pl[4][16 * 64];

  // K staging coords (gload_lds, linear dest, pre-swizzled source)
  int s_row = tid >> 3;                                  // 0..31 (+32*i)
  int s_srccol = ((tid & 7) ^ ((tid >> 3) & 7)) * 8;     // swizzled global d-chunk

  unsigned short* myP = &Pl[wid][0];
  f32x4 zero = {0.f, 0.f, 0.f, 0.f};

  for (int half = 0; half < 2; ++half) {
    int qt = (half == 0) ? pairIdx : 31 - pairIdx;
    int q0 = qt * 64;
    int nkv = qt + 1;

    // Q fragments: wave owns rows q0 + wid*16 .. +15
    bf16x8 aq[2];
    #pragma unroll
    for (int kk = 0; kk < 2; ++kk)
      aq[kk] = *(const bf16x8*)(qkv + (size_t)(tb + q0 + wid * 16 + lrow) * LDQ + qcol + kk * 32 + kgrp);

    f32x4 oacc[4];
    #pragma unroll
    for (int e = 0; e < 4; ++e) oacc[e] = zero;
    float mrun[4], lrun[4];
    #pragma unroll
    for (int r = 0; r < 4; ++r) { mrun[r] = -1e30f; lrun[r] = 0.0f; }

    int cur = 0;
    bf16x8 vreg[2];

    // ---- prologue: stage KV tile 0 into buf 0 ----
    #pragma unroll
    for (int i = 0; i < 2; ++i)
      gload_lds16(qkv + (size_t)(tb + i * 32 + s_row) * LDQ + kcol + s_srccol,
                  (char*)Ks[0] + i * 4096 + tid * 16);
    #pragma unroll
    for (int i = 0; i < 2; ++i) {
      int chunk = i * 256 + tid;
      vreg[i] = *(const bf16x8*)(qkv + (size_t)(tb + (chunk >> 3)) * LDQ + vcol + (chunk & 7) * 8);
    }
    #pragma unroll
    for (int i = 0; i < 2; ++i) {
      int chunk = i * 256 + tid;
      int t = chunk >> 3, e0 = (chunk & 7) * 8;
      #pragma unroll
      for (int jj = 0; jj < 8; ++jj) {
        int e = e0 + jj;
        int byteoff = e * 128 + ((((t >> 3) ^ (e & 7) ^ (e >> 3)) & 7) << 4) + (t & 7) * 2;
        *(unsigned short*)((char*)Vt[0] + byteoff) = (unsigned short)vreg[i][jj];
      }
    }

    for (int j = 0; j < nkv; ++j) {
      __syncthreads();   // staging of buf[cur] complete; prior reads of buf[cur^1] done
      int nxt = cur ^ 1;
      bool pf = (j + 1 < nkv);
      if (pf) {
        // issue next K tile (async to LDS) + next V tile (to regs) EARLY
        #pragma unroll
        for (int i = 0; i < 2; ++i)
          gload_lds16(qkv + (size_t)(tb + (j + 1) * 64 + i * 32 + s_row) * LDQ + kcol + s_srccol,
                      (char*)Ks[nxt] + i * 4096 + tid * 16);
        #pragma unroll
        for (int i = 0; i < 2; ++i) {
          int chunk = i * 256 + tid;
          vreg[i] = *(const bf16x8*)(qkv + (size_t)(tb + (j + 1) * 64 + (chunk >> 3)) * LDQ + vcol + (chunk & 7) * 8);
        }
      }

      // ---- S = Q K^T (16 q-rows x 64 keys per wave) ----
      f32x4 sacc[4];
      #pragma unroll
      for (int n = 0; n < 4; ++n) sacc[n] = zero;
      #pragma unroll
      for (int n = 0; n < 4; ++n) {
        int trow = n * 16 + lrow;
        #pragma unroll
        for (int kk = 0; kk < 2; ++kk) {
          int byteoff = trow * 128 + (((kk * 4 + g) ^ (trow & 7)) << 4);
          bf16x8 bk = *(const bf16x8*)((const char*)Ks[cur] + byteoff);
          sacc[n] = __builtin_amdgcn_mfma_f32_16x16x32_bf16(aq[kk], bk, sacc[n], 0, 0, 0);
        }
      }

      // ---- online softmax ----
      bool diag = (j == qt);
      float pv[4][4];
      #pragma unroll
      for (int r = 0; r < 4; ++r) {
        int sg = q0 + wid * 16 + g * 4 + r;          // global query index
        float mx = -1e30f;
        #pragma unroll
        for (int n = 0; n < 4; ++n) {
          float sv = sacc[n][r] * 0.125f;
          int tg = j * 64 + n * 16 + lrow;           // global key index
          if (diag && tg > sg) sv = -1e30f;
          pv[r][n] = sv;
          mx = fmaxf(mx, sv);
        }
        #pragma unroll
        for (int off = 1; off < 16; off <<= 1) mx = fmaxf(mx, __shfl_xor(mx, off, 64));
        float mnew = fmaxf(mrun[r], mx);
        float esc = __expf(mrun[r] - mnew);
        float rsum = 0.f;
        #pragma unroll
        for (int n = 0; n < 4; ++n) {
          float p = __expf(pv[r][n] - mnew);
          pv[r][n] = p;
          rsum += p;
        }
        #pragma unroll
        for (int off = 1; off < 16; off <<= 1) rsum += __shfl_xor(rsum, off, 64);
        lrun[r] = lrun[r] * esc + rsum;
        mrun[r] = mnew;
        #pragma unroll
        for (int e = 0; e < 4; ++e) oacc[e][r] *= esc;
      }

      // ---- write next V tile into LDS (swizzled transpose), latency already hidden ----
      if (pf) {
        #pragma unroll
        for (int i = 0; i < 2; ++i) {
          int chunk = i * 256 + tid;
          int t = chunk >> 3, e0 = (chunk & 7) * 8;
          #pragma unroll
          for (int jj = 0; jj < 8; ++jj) {
            int e = e0 + jj;
            int byteoff = e * 128 + ((((t >> 3) ^ (e & 7) ^ (e >> 3)) & 7) << 4) + (t & 7) * 2;
            *(unsigned short*)((char*)Vt[nxt] + byteoff) = (unsigned short)vreg[i][jj];
          }
        }
      }

      // ---- write P (wave-private, swizzled) ----
      #pragma unroll
      for (int r = 0; r < 4; ++r) {
        int q = g * 4 + r;
        #pragma unroll
        for (int n = 0; n < 4; ++n) {
          int t = n * 16 + lrow;
          int byteoff = q * 128 + ((((t >> 3) ^ (q & 7)) & 7) << 4) + (t & 7) * 2;
          *(unsigned short*)((char*)myP + byteoff) = f2bf(pv[r][n]);
        }
      }

      // ---- O += P V (in-wave LDS dependency; compiler inserts lgkmcnt) ----
      #pragma unroll
      for (int kk = 0; kk < 2; ++kk) {
        int pbyte = lrow * 128 + (((kk * 4 + g) ^ (lrow & 7)) << 4);
        bf16x8 ap = *(const bf16x8*)((const char*)myP + pbyte);
        #pragma unroll
        for (int e = 0; e < 4; ++e) {
          int erow = e * 16 + lrow;
          int vbyte = erow * 128 + ((((kk * 4 + g) ^ (erow & 7) ^ (erow >> 3)) & 7) << 4);
          bf16x8 bv = *(const bf16x8*)((const char*)Vt[cur] + vbyte);
          oacc[e] = __builtin_amdgcn_mfma_f32_16x16x32_bf16(ap, bv, oacc[e], 0, 0, 0);
        }
      }
      cur = nxt;
    }

    // ---- epilogue: out = x + O / l ----
    #pragma unroll
    for (int r = 0; r < 4; ++r) {
      float inv = 1.0f / lrun[r];
      int row = tb + q0 + wid * 16 + g * 4 + r;
      #pragma unroll
      for (int e = 0; e < 4; ++e) {
        size_t idx = (size_t)row * 1024 + h * 64 + e * 16 + lrow;
        out[idx] = x[idx] + oacc[e][r] * inv;
      }
    }
  }
}

// ---------------- launch ----------------
extern "C" void kernel_launch(void* const* d_in, const int* in_sizes, int n_in,
                              void* d_out, int out_size, void* d_ws, size_t ws_size,
                              hipStream_t stream) {
  (void)in_sizes; (void)n_in; (void)out_size; (void)ws_size;
  const float* x    = (const float*)d_in[0];
  const float* Wq   = (const float*)d_in[1];
  const float* bq   = (const float*)d_in[2];
  const float* Wk   = (const float*)d_in[3];
  const float* bk   = (const float*)d_in[4];
  const float* Wv   = (const float*)d_in[5];
  const float* bv   = (const float*)d_in[6];
  const float* ln1g = (const float*)d_in[7];
  const float* ln1b = (const float*)d_in[8];
  const float* ln2g = (const float*)d_in[9];
  const float* ln2b = (const float*)d_in[10];
  const float* W1   = (const float*)d_in[11];
  const float* b1   = (const float*)d_in[12];
  const float* W2   = (const float*)d_in[13];
  const float* b2   = (const float*)d_in[14];
  float* out = (float*)d_out;
  char* ws = (char*)d_ws;

  unsigned short* h1    = (unsigned short*)(ws + 0);          // 8 MiB  [4096][1024] bf16
  unsigned short* wqkvT = (unsigned short*)(ws + 8388608);    // 6 MiB  [3072][1024] bf16
  unsigned short* w1T   = (unsigned short*)(ws + 14680064);   // 8 MiB  [4096][1024] bf16
  unsigned short* w2T   = (unsigned short*)(ws + 23068672);   // 8 MiB  [1024][4096] bf16
  float*          bqkv  = (float*)(ws + 31457280);            // 12 KiB [3072] f32
  unsigned short* qkv   = (unsigned short*)(ws + 33554432);   // 24 MiB [4096][3072] bf16
  unsigned short* fbuf  = (unsigned short*)(ws + 33554432);   // 32 MiB [4096][4096] bf16 (overlaps qkv; qkv dead by then)

  dim3 tb(32, 8);
  // Wq/Wk/Wv: [16][1024][64] -> [16][64][1024] concat into wqkvT
  k_transpose<<<dim3(2, 32, 16), tb, 0, stream>>>(Wq, wqkvT,               1024, 64, 1024L * 64, 64L * 1024);
  k_transpose<<<dim3(2, 32, 16), tb, 0, stream>>>(Wk, wqkvT + 1024 * 1024, 1024, 64, 1024L * 64, 64L * 1024);
  k_transpose<<<dim3(2, 32, 16), tb, 0, stream>>>(Wv, wqkvT + 2048 * 1024, 1024, 64, 1024L * 64, 64L * 1024);
  // W1: [1024][4096] -> w1T [4096][1024]
  k_transpose<<<dim3(128, 32, 1), tb, 0, stream>>>(W1, w1T, 1024, 4096, 0, 0);
  // W2: [4096][1024] -> w2T [1024][4096]
  k_transpose<<<dim3(32, 128, 1), tb, 0, stream>>>(W2, w2T, 4096, 1024, 0, 0);
  k_concat_bias<<<12, 256, 0, stream>>>(bq, bk, bv, bqkv);

  // LN1
  k_ln_bf16<<<4096, 256, 0, stream>>>(x, ln1g, ln1b, h1);
  // QKV projection: [4096][1024] x [1024][3072] -> qkv bf16
  k_gemm_bt<0><<<dim3(24, 32), 256, 0, stream>>>(h1, wqkvT, bqkv, qkv, 4096, 3072, 1024);
  // attention + residual: out = x + attn  (512 balanced blocks)
  k_flash_attn<<<512, 256, 0, stream>>>(qkv, x, out);
  // LN2 (reads out)
  k_ln_bf16<<<4096, 256, 0, stream>>>(out, ln2g, ln2b, h1);
  // FFN1 + GELU: [4096][1024] x [1024][4096] -> fbuf bf16
  k_gemm_bt<1><<<dim3(32, 32), 256, 0, stream>>>(h1, w1T, b1, fbuf, 4096, 4096, 1024);
  // FFN2: [4096][4096] x [4096][1024] += out
  k_gemm_bt<2><<<dim3(8, 32), 256, 0, stream>>>(fbuf, w2T, b2, out, 4096, 1024, 4096);
}

// Round 4
// 392.143 us; speedup vs baseline: 1.4742x; 1.1498x over previous
//
#include <hip/hip_runtime.h>
#include <hip/hip_bf16.h>
#include <cstdint>
#include <cstddef>

// Problem constants
// B=2, S=2048, D=1024, H=16, DH=64, FF=4096, M=B*S=4096

typedef short bf16x8 __attribute__((ext_vector_type(8)));
typedef float f32x4 __attribute__((ext_vector_type(4)));

#define DEV static __device__ __forceinline__

DEV unsigned short f2bf(float f) {
  union { float fv; unsigned u; } a; a.fv = f;
  unsigned r = a.u + 0x7FFFu + ((a.u >> 16) & 1u);
  return (unsigned short)(r >> 16);
}

DEV void gload_lds16(const void* g, void* l) {
  __builtin_amdgcn_global_load_lds(
      (const __attribute__((address_space(1))) unsigned int*)g,
      (__attribute__((address_space(3))) unsigned int*)l,
      16, 0, 0);
}

// ---------------- transpose f32 [batch][R][C] -> bf16 [batch][C][R] ----------------
__global__ __launch_bounds__(256) void k_transpose(const float* __restrict__ in,
                                                   unsigned short* __restrict__ out,
                                                   int R, int C,
                                                   long inBatchStride, long outBatchStride) {
  __shared__ float tile[32][33];
  long batch = blockIdx.z;
  int c0 = blockIdx.x * 32;
  int r0 = blockIdx.y * 32;
  const float* src = in + batch * inBatchStride;
  unsigned short* dst = out + batch * outBatchStride;
  int tx = threadIdx.x, ty = threadIdx.y;  // (32, 8)
  #pragma unroll
  for (int i = ty; i < 32; i += 8)
    tile[i][tx] = src[(long)(r0 + i) * C + (c0 + tx)];
  __syncthreads();
  #pragma unroll
  for (int i = ty; i < 32; i += 8)
    dst[(long)(c0 + i) * R + (r0 + tx)] = f2bf(tile[tx][i]);
}

// ---------------- concat q/k/v biases into one [3072] vector ----------------
__global__ void k_concat_bias(const float* __restrict__ bq, const float* __restrict__ bk,
                              const float* __restrict__ bv, float* __restrict__ out) {
  int i = blockIdx.x * 256 + threadIdx.x;
  if (i < 1024) out[i] = bq[i];
  else if (i < 2048) out[i] = bk[i - 1024];
  else if (i < 3072) out[i] = bv[i - 2048];
}

// ---------------- LayerNorm f32 [4096][1024] -> bf16 ----------------
__global__ __launch_bounds__(256) void k_ln_bf16(const float* __restrict__ x,
                                                 const float* __restrict__ g,
                                                 const float* __restrict__ b,
                                                 unsigned short* __restrict__ out) {
  int row = blockIdx.x;
  const float* xr = x + (size_t)row * 1024;
  int t = threadIdx.x;
  float4 v = *(const float4*)(xr + t * 4);
  float s = v.x + v.y + v.z + v.w;
  float s2 = v.x * v.x + v.y * v.y + v.z * v.z + v.w * v.w;
  for (int off = 32; off > 0; off >>= 1) {
    s  += __shfl_down(s,  off, 64);
    s2 += __shfl_down(s2, off, 64);
  }
  __shared__ float ws1[4], ws2[4];
  __shared__ float mu_s, rs_s;
  int wid = t >> 6, lane = t & 63;
  if (lane == 0) { ws1[wid] = s; ws2[wid] = s2; }
  __syncthreads();
  if (t == 0) {
    float S1 = ws1[0] + ws1[1] + ws1[2] + ws1[3];
    float S2 = ws2[0] + ws2[1] + ws2[2] + ws2[3];
    float mu = S1 * (1.0f / 1024.0f);
    float var = S2 * (1.0f / 1024.0f) - mu * mu;
    mu_s = mu;
    rs_s = rsqrtf(var + 1e-5f);
  }
  __syncthreads();
  float mu = mu_s, rs = rs_s;
  float4 gv = *(const float4*)(g + t * 4);
  float4 bv = *(const float4*)(b + t * 4);
  ushort4 o;
  o.x = f2bf((v.x - mu) * rs * gv.x + bv.x);
  o.y = f2bf((v.y - mu) * rs * gv.y + bv.y);
  o.z = f2bf((v.z - mu) * rs * gv.z + bv.z);
  o.w = f2bf((v.w - mu) * rs * gv.w + bv.w);
  *(ushort4*)(out + (size_t)row * 1024 + t * 4) = o;
}

// ---------------- GEMM: C[M][N] = A[M][K] * Bt[N][K]^T + bias ----------------
// EPI 0: store bf16; EPI 1: gelu(exact)+store bf16; EPI 2: f32 atomicAdd (+bias when kp==0)
// 1-D grid of nbx*nby*kparts blocks, XCD-swizzled (grid must be divisible by 8).
// LDS tiles [128 rows][8 chunks of 16B], chunk slot c holds global chunk c ^ (row&7)
// (involution; staged via gload_lds with pre-swizzled SOURCE column, read with same XOR).
template <int EPI>
__global__ __launch_bounds__(256) void k_gemm_bt(const unsigned short* __restrict__ A,
                                                 const unsigned short* __restrict__ Bt,
                                                 const float* __restrict__ bias,
                                                 void* __restrict__ Cout,
                                                 int M, int N, int K,
                                                 int nbx, int nby, int kparts) {
  __shared__ __align__(16) unsigned short As[128 * 64];
  __shared__ __align__(16) unsigned short Bs[128 * 64];
  int tid = threadIdx.x;

  int nwg = nbx * nby * kparts;
  int flat = blockIdx.x;
  int swz = (flat & 7) * (nwg >> 3) + (flat >> 3);   // XCD-contiguous logical id
  int bx = swz % nbx;
  int rest = swz / nbx;
  int by = rest % nby;
  int kp = rest / nby;
  int col0 = bx * 128;
  int row0 = by * 128;
  int kLen = K / kparts;
  int kBeg = kp * kLen;

  int wid = tid >> 6, lane = tid & 63;
  int wr = wid >> 1, wc = wid & 1;
  int lrow = lane & 15;
  int g = lane >> 4;
  int s_row = tid >> 3;                                // dest row within 32-row slab
  int s_scol = ((tid & 7) ^ (s_row & 7)) * 8;          // pre-swizzled global k-chunk

  f32x4 acc[4][4];
  f32x4 zero = {0.f, 0.f, 0.f, 0.f};
  #pragma unroll
  for (int m = 0; m < 4; ++m)
    #pragma unroll
    for (int n = 0; n < 4; ++n) acc[m][n] = zero;

  for (int k0 = kBeg; k0 < kBeg + kLen; k0 += 64) {
    #pragma unroll
    for (int i = 0; i < 4; ++i) {
      int r = i * 32 + s_row;
      gload_lds16(A  + (size_t)(row0 + r) * K + k0 + s_scol, (char*)As + i * 4096 + tid * 16);
      gload_lds16(Bt + (size_t)(col0 + r) * K + k0 + s_scol, (char*)Bs + i * 4096 + tid * 16);
    }
    __syncthreads();
    bf16x8 af[4][2], bf[4][2];
    #pragma unroll
    for (int m = 0; m < 4; ++m) {
      int ra = wr * 64 + m * 16 + lrow;
      #pragma unroll
      for (int kk = 0; kk < 2; ++kk) {
        int byteoff = ra * 128 + (((kk * 4 + g) ^ (lrow & 7)) << 4);
        af[m][kk] = *(const bf16x8*)((const char*)As + byteoff);
      }
    }
    #pragma unroll
    for (int n = 0; n < 4; ++n) {
      int rb = wc * 64 + n * 16 + lrow;
      #pragma unroll
      for (int kk = 0; kk < 2; ++kk) {
        int byteoff = rb * 128 + (((kk * 4 + g) ^ (lrow & 7)) << 4);
        bf[n][kk] = *(const bf16x8*)((const char*)Bs + byteoff);
      }
    }
    #pragma unroll
    for (int m = 0; m < 4; ++m)
      #pragma unroll
      for (int n = 0; n < 4; ++n)
        #pragma unroll
        for (int kk = 0; kk < 2; ++kk)
          acc[m][n] = __builtin_amdgcn_mfma_f32_16x16x32_bf16(af[m][kk], bf[n][kk], acc[m][n], 0, 0, 0);
    __syncthreads();
  }

  int rbase = row0 + wr * 64 + g * 4;
  int cbase = col0 + wc * 64 + lrow;
  #pragma unroll
  for (int m = 0; m < 4; ++m) {
    #pragma unroll
    for (int n = 0; n < 4; ++n) {
      int col = cbase + n * 16;
      float bia = bias[col];
      #pragma unroll
      for (int j = 0; j < 4; ++j) {
        int row = rbase + m * 16 + j;
        float v = acc[m][n][j];
        if constexpr (EPI == 0) {
          ((unsigned short*)Cout)[(size_t)row * N + col] = f2bf(v + bia);
        } else if constexpr (EPI == 1) {
          float u = v + bia;
          float gel = 0.5f * u * (1.0f + erff(u * 0.70710678118f));
          ((unsigned short*)Cout)[(size_t)row * N + col] = f2bf(gel);
        } else {
          float u = v + (kp == 0 ? bia : 0.0f);
          atomicAdd((float*)Cout + (size_t)row * N + col, u);
        }
      }
    }
  }
}

// ---------------- fused causal flash attention + residual ----------------
// qkv: bf16 [4096][3072] (Q|K|V per head concat); x: f32 [4096][1024]; out = x + attn
// Grid: 512 blocks = 32 (b*h) x 16 q-tile pairs (p, 31-p) -> 33 KV-tile iters each.
// LDS layouts XOR-chunk-swizzled (16B chunks, row stride 128B):
//   Ks[buf][row t][chunk c]: holds global d-chunk c ^ (t&7)   (staged via gload_lds w/ pre-swizzled src)
//   Vt[buf][row e][chunk c]: holds global t-chunk c ^ (e&7) ^ (e>>3)
//   Pl[wave][row q][chunk c]: holds t-chunk c ^ (q&7)
__global__ __launch_bounds__(256) void k_flash_attn(const unsigned short* __restrict__ qkv,
                                                    const float* __restrict__ x,
                                                    float* __restrict__ out) {
  int blk = blockIdx.x;
  int pairIdx = blk & 15;
  int bh = blk >> 4;
  int b = bh >> 4, h = bh & 15;
  const int LDQ = 3072;
  int tb = b * 2048;
  int qcol = h * 64, kcol = 1024 + h * 64, vcol = 2048 + h * 64;
  int tid = threadIdx.x, wid = tid >> 6, lane = tid & 63;
  int lrow = lane & 15;
  int g = lane >> 4;
  int kgrp = g * 8;

  __shared__ __align__(16) unsigned short Ks[2][64 * 64];
  __shared__ __align__(16) unsigned short Vt[2][64 * 64];
  __shared__ __align__(16) unsigned short Pl[4][16 * 64];

  // K staging coords (gload_lds, linear dest, pre-swizzled source)
  int s_row = tid >> 3;                                  // 0..31 (+32*i)
  int s_srccol = ((tid & 7) ^ ((tid >> 3) & 7)) * 8;     // swizzled global d-chunk

  unsigned short* myP = &Pl[wid][0];
  f32x4 zero = {0.f, 0.f, 0.f, 0.f};

  for (int half = 0; half < 2; ++half) {
    int qt = (half == 0) ? pairIdx : 31 - pairIdx;
    int q0 = qt * 64;
    int nkv = qt + 1;

    // Q fragments: wave owns rows q0 + wid*16 .. +15
    bf16x8 aq[2];
    #pragma unroll
    for (int kk = 0; kk < 2; ++kk)
      aq[kk] = *(const bf16x8*)(qkv + (size_t)(tb + q0 + wid * 16 + lrow) * LDQ + qcol + kk * 32 + kgrp);

    f32x4 oacc[4];
    #pragma unroll
    for (int e = 0; e < 4; ++e) oacc[e] = zero;
    float mrun[4], lrun[4];
    #pragma unroll
    for (int r = 0; r < 4; ++r) { mrun[r] = -1e30f; lrun[r] = 0.0f; }

    int cur = 0;
    bf16x8 vreg[2];

    // ---- prologue: stage KV tile 0 into buf 0 ----
    #pragma unroll
    for (int i = 0; i < 2; ++i)
      gload_lds16(qkv + (size_t)(tb + i * 32 + s_row) * LDQ + kcol + s_srccol,
                  (char*)Ks[0] + i * 4096 + tid * 16);
    #pragma unroll
    for (int i = 0; i < 2; ++i) {
      int chunk = i * 256 + tid;
      vreg[i] = *(const bf16x8*)(qkv + (size_t)(tb + (chunk >> 3)) * LDQ + vcol + (chunk & 7) * 8);
    }
    #pragma unroll
    for (int i = 0; i < 2; ++i) {
      int chunk = i * 256 + tid;
      int t = chunk >> 3, e0 = (chunk & 7) * 8;
      #pragma unroll
      for (int jj = 0; jj < 8; ++jj) {
        int e = e0 + jj;
        int byteoff = e * 128 + ((((t >> 3) ^ (e & 7) ^ (e >> 3)) & 7) << 4) + (t & 7) * 2;
        *(unsigned short*)((char*)Vt[0] + byteoff) = (unsigned short)vreg[i][jj];
      }
    }

    for (int j = 0; j < nkv; ++j) {
      __syncthreads();   // staging of buf[cur] complete; prior reads of buf[cur^1] done
      int nxt = cur ^ 1;
      bool pf = (j + 1 < nkv);
      if (pf) {
        // issue next K tile (async to LDS) + next V tile (to regs) EARLY
        #pragma unroll
        for (int i = 0; i < 2; ++i)
          gload_lds16(qkv + (size_t)(tb + (j + 1) * 64 + i * 32 + s_row) * LDQ + kcol + s_srccol,
                      (char*)Ks[nxt] + i * 4096 + tid * 16);
        #pragma unroll
        for (int i = 0; i < 2; ++i) {
          int chunk = i * 256 + tid;
          vreg[i] = *(const bf16x8*)(qkv + (size_t)(tb + (j + 1) * 64 + (chunk >> 3)) * LDQ + vcol + (chunk & 7) * 8);
        }
      }

      // ---- S = Q K^T (16 q-rows x 64 keys per wave) ----
      f32x4 sacc[4];
      #pragma unroll
      for (int n = 0; n < 4; ++n) sacc[n] = zero;
      __builtin_amdgcn_s_setprio(1);
      #pragma unroll
      for (int n = 0; n < 4; ++n) {
        int trow = n * 16 + lrow;
        #pragma unroll
        for (int kk = 0; kk < 2; ++kk) {
          int byteoff = trow * 128 + (((kk * 4 + g) ^ (trow & 7)) << 4);
          bf16x8 bk = *(const bf16x8*)((const char*)Ks[cur] + byteoff);
          sacc[n] = __builtin_amdgcn_mfma_f32_16x16x32_bf16(aq[kk], bk, sacc[n], 0, 0, 0);
        }
      }
      __builtin_amdgcn_s_setprio(0);

      // ---- online softmax ----
      bool diag = (j == qt);
      float pv[4][4];
      #pragma unroll
      for (int r = 0; r < 4; ++r) {
        int sg = q0 + wid * 16 + g * 4 + r;          // global query index
        float mx = -1e30f;
        #pragma unroll
        for (int n = 0; n < 4; ++n) {
          float sv = sacc[n][r] * 0.125f;
          int tg = j * 64 + n * 16 + lrow;           // global key index
          if (diag && tg > sg) sv = -1e30f;
          pv[r][n] = sv;
          mx = fmaxf(mx, sv);
        }
        #pragma unroll
        for (int off = 1; off < 16; off <<= 1) mx = fmaxf(mx, __shfl_xor(mx, off, 64));
        float mnew = fmaxf(mrun[r], mx);
        float esc = __expf(mrun[r] - mnew);
        float rsum = 0.f;
        #pragma unroll
        for (int n = 0; n < 4; ++n) {
          float p = __expf(pv[r][n] - mnew);
          pv[r][n] = p;
          rsum += p;
        }
        #pragma unroll
        for (int off = 1; off < 16; off <<= 1) rsum += __shfl_xor(rsum, off, 64);
        lrun[r] = lrun[r] * esc + rsum;
        mrun[r] = mnew;
        #pragma unroll
        for (int e = 0; e < 4; ++e) oacc[e][r] *= esc;
      }

      // ---- write next V tile into LDS (swizzled transpose), latency already hidden ----
      if (pf) {
        #pragma unroll
        for (int i = 0; i < 2; ++i) {
          int chunk = i * 256 + tid;
          int t = chunk >> 3, e0 = (chunk & 7) * 8;
          #pragma unroll
          for (int jj = 0; jj < 8; ++jj) {
            int e = e0 + jj;
            int byteoff = e * 128 + ((((t >> 3) ^ (e & 7) ^ (e >> 3)) & 7) << 4) + (t & 7) * 2;
            *(unsigned short*)((char*)Vt[nxt] + byteoff) = (unsigned short)vreg[i][jj];
          }
        }
      }

      // ---- write P (wave-private, swizzled) ----
      #pragma unroll
      for (int r = 0; r < 4; ++r) {
        int q = g * 4 + r;
        #pragma unroll
        for (int n = 0; n < 4; ++n) {
          int t = n * 16 + lrow;
          int byteoff = q * 128 + ((((t >> 3) ^ (q & 7)) & 7) << 4) + (t & 7) * 2;
          *(unsigned short*)((char*)myP + byteoff) = f2bf(pv[r][n]);
        }
      }

      // ---- O += P V (in-wave LDS dependency; compiler inserts lgkmcnt) ----
      __builtin_amdgcn_s_setprio(1);
      #pragma unroll
      for (int kk = 0; kk < 2; ++kk) {
        int pbyte = lrow * 128 + (((kk * 4 + g) ^ (lrow & 7)) << 4);
        bf16x8 ap = *(const bf16x8*)((const char*)myP + pbyte);
        #pragma unroll
        for (int e = 0; e < 4; ++e) {
          int erow = e * 16 + lrow;
          int vbyte = erow * 128 + ((((kk * 4 + g) ^ (erow & 7) ^ (erow >> 3)) & 7) << 4);
          bf16x8 bv = *(const bf16x8*)((const char*)Vt[cur] + vbyte);
          oacc[e] = __builtin_amdgcn_mfma_f32_16x16x32_bf16(ap, bv, oacc[e], 0, 0, 0);
        }
      }
      __builtin_amdgcn_s_setprio(0);
      cur = nxt;
    }

    // ---- epilogue: out = x + O / l ----
    #pragma unroll
    for (int r = 0; r < 4; ++r) {
      float inv = 1.0f / lrun[r];
      int row = tb + q0 + wid * 16 + g * 4 + r;
      #pragma unroll
      for (int e = 0; e < 4; ++e) {
        size_t idx = (size_t)row * 1024 + h * 64 + e * 16 + lrow;
        out[idx] = x[idx] + oacc[e][r] * inv;
      }
    }
  }
}

// ---------------- launch ----------------
extern "C" void kernel_launch(void* const* d_in, const int* in_sizes, int n_in,
                              void* d_out, int out_size, void* d_ws, size_t ws_size,
                              hipStream_t stream) {
  (void)in_sizes; (void)n_in; (void)out_size; (void)ws_size;
  const float* x    = (const float*)d_in[0];
  const float* Wq   = (const float*)d_in[1];
  const float* bq   = (const float*)d_in[2];
  const float* Wk   = (const float*)d_in[3];
  const float* bk   = (const float*)d_in[4];
  const float* Wv   = (const float*)d_in[5];
  const float* bv   = (const float*)d_in[6];
  const float* ln1g = (const float*)d_in[7];
  const float* ln1b = (const float*)d_in[8];
  const float* ln2g = (const float*)d_in[9];
  const float* ln2b = (const float*)d_in[10];
  const float* W1   = (const float*)d_in[11];
  const float* b1   = (const float*)d_in[12];
  const float* W2   = (const float*)d_in[13];
  const float* b2   = (const float*)d_in[14];
  float* out = (float*)d_out;
  char* ws = (char*)d_ws;

  unsigned short* h1    = (unsigned short*)(ws + 0);          // 8 MiB  [4096][1024] bf16
  unsigned short* wqkvT = (unsigned short*)(ws + 8388608);    // 6 MiB  [3072][1024] bf16
  unsigned short* w1T   = (unsigned short*)(ws + 14680064);   // 8 MiB  [4096][1024] bf16
  unsigned short* w2T   = (unsigned short*)(ws + 23068672);   // 8 MiB  [1024][4096] bf16
  float*          bqkv  = (float*)(ws + 31457280);            // 12 KiB [3072] f32
  unsigned short* qkv   = (unsigned short*)(ws + 33554432);   // 24 MiB [4096][3072] bf16
  unsigned short* fbuf  = (unsigned short*)(ws + 33554432);   // 32 MiB [4096][4096] bf16 (overlaps qkv; qkv dead by then)

  dim3 tb(32, 8);
  // Wq/Wk/Wv: [16][1024][64] -> [16][64][1024] concat into wqkvT
  k_transpose<<<dim3(2, 32, 16), tb, 0, stream>>>(Wq, wqkvT,               1024, 64, 1024L * 64, 64L * 1024);
  k_transpose<<<dim3(2, 32, 16), tb, 0, stream>>>(Wk, wqkvT + 1024 * 1024, 1024, 64, 1024L * 64, 64L * 1024);
  k_transpose<<<dim3(2, 32, 16), tb, 0, stream>>>(Wv, wqkvT + 2048 * 1024, 1024, 64, 1024L * 64, 64L * 1024);
  // W1: [1024][4096] -> w1T [4096][1024]
  k_transpose<<<dim3(128, 32, 1), tb, 0, stream>>>(W1, w1T, 1024, 4096, 0, 0);
  // W2: [4096][1024] -> w2T [1024][4096]
  k_transpose<<<dim3(32, 128, 1), tb, 0, stream>>>(W2, w2T, 4096, 1024, 0, 0);
  k_concat_bias<<<12, 256, 0, stream>>>(bq, bk, bv, bqkv);

  // LN1
  k_ln_bf16<<<4096, 256, 0, stream>>>(x, ln1g, ln1b, h1);
  // QKV projection: [4096][1024] x [1024][3072] -> qkv bf16 (768 blocks, XCD-swizzled)
  k_gemm_bt<0><<<768, 256, 0, stream>>>(h1, wqkvT, bqkv, qkv, 4096, 3072, 1024, 24, 32, 1);
  // attention + residual: out = x + attn  (512 balanced blocks)
  k_flash_attn<<<512, 256, 0, stream>>>(qkv, x, out);
  // LN2 (reads out)
  k_ln_bf16<<<4096, 256, 0, stream>>>(out, ln2g, ln2b, h1);
  // FFN1 + GELU: [4096][1024] x [1024][4096] -> fbuf bf16 (1024 blocks)
  k_gemm_bt<1><<<1024, 256, 0, stream>>>(h1, w1T, b1, fbuf, 4096, 4096, 1024, 32, 32, 1);
  // FFN2: [4096][4096] x [4096][1024] += out (split-K=2, atomic f32 accumulate)
  k_gemm_bt<2><<<512, 256, 0, stream>>>(fbuf, w2T, b2, out, 4096, 1024, 4096, 8, 32, 2);
}

// Round 8
// 388.226 us; speedup vs baseline: 1.4891x; 1.0101x over previous
//
#include <hip/hip_runtime.h>
#include <hip/hip_bf16.h>
#include <cstdint>
#include <cstddef>

// Problem constants
// B=2, S=2048, D=1024, H=16, DH=64, FF=4096, M=B*S=4096

typedef short bf16x8 __attribute__((ext_vector_type(8)));
typedef float f32x4 __attribute__((ext_vector_type(4)));

#define DEV static __device__ __forceinline__

DEV unsigned short f2bf(float f) {
  union { float fv; unsigned u; } a; a.fv = f;
  unsigned r = a.u + 0x7FFFu + ((a.u >> 16) & 1u);
  return (unsigned short)(r >> 16);
}

DEV void gload_lds16(const void* g, void* l) {
  __builtin_amdgcn_global_load_lds(
      (const __attribute__((address_space(1))) unsigned int*)g,
      (__attribute__((address_space(3))) unsigned int*)l,
      16, 0, 0);
}

// ---------------- transpose f32 [batch][R][C] -> bf16 [batch][C][R] ----------------
__global__ __launch_bounds__(256) void k_transpose(const float* __restrict__ in,
                                                   unsigned short* __restrict__ out,
                                                   int R, int C,
                                                   long inBatchStride, long outBatchStride) {
  __shared__ float tile[32][33];
  long batch = blockIdx.z;
  int c0 = blockIdx.x * 32;
  int r0 = blockIdx.y * 32;
  const float* src = in + batch * inBatchStride;
  unsigned short* dst = out + batch * outBatchStride;
  int tx = threadIdx.x, ty = threadIdx.y;  // (32, 8)
  #pragma unroll
  for (int i = ty; i < 32; i += 8)
    tile[i][tx] = src[(long)(r0 + i) * C + (c0 + tx)];
  __syncthreads();
  #pragma unroll
  for (int i = ty; i < 32; i += 8)
    dst[(long)(c0 + i) * R + (r0 + tx)] = f2bf(tile[tx][i]);
}

// ---------------- concat q/k/v biases into one [3072] vector ----------------
__global__ void k_concat_bias(const float* __restrict__ bq, const float* __restrict__ bk,
                              const float* __restrict__ bv, float* __restrict__ out) {
  int i = blockIdx.x * 256 + threadIdx.x;
  if (i < 1024) out[i] = bq[i];
  else if (i < 2048) out[i] = bk[i - 1024];
  else if (i < 3072) out[i] = bv[i - 2048];
}

// ---------------- LayerNorm f32 [4096][1024] -> bf16 ----------------
__global__ __launch_bounds__(256) void k_ln_bf16(const float* __restrict__ x,
                                                 const float* __restrict__ g,
                                                 const float* __restrict__ b,
                                                 unsigned short* __restrict__ out) {
  int row = blockIdx.x;
  const float* xr = x + (size_t)row * 1024;
  int t = threadIdx.x;
  float4 v = *(const float4*)(xr + t * 4);
  float s = v.x + v.y + v.z + v.w;
  float s2 = v.x * v.x + v.y * v.y + v.z * v.z + v.w * v.w;
  for (int off = 32; off > 0; off >>= 1) {
    s  += __shfl_down(s,  off, 64);
    s2 += __shfl_down(s2, off, 64);
  }
  __shared__ float ws1[4], ws2[4];
  __shared__ float mu_s, rs_s;
  int wid = t >> 6, lane = t & 63;
  if (lane == 0) { ws1[wid] = s; ws2[wid] = s2; }
  __syncthreads();
  if (t == 0) {
    float S1 = ws1[0] + ws1[1] + ws1[2] + ws1[3];
    float S2 = ws2[0] + ws2[1] + ws2[2] + ws2[3];
    float mu = S1 * (1.0f / 1024.0f);
    float var = S2 * (1.0f / 1024.0f) - mu * mu;
    mu_s = mu;
    rs_s = rsqrtf(var + 1e-5f);
  }
  __syncthreads();
  float mu = mu_s, rs = rs_s;
  float4 gv = *(const float4*)(g + t * 4);
  float4 bv = *(const float4*)(b + t * 4);
  ushort4 o;
  o.x = f2bf((v.x - mu) * rs * gv.x + bv.x);
  o.y = f2bf((v.y - mu) * rs * gv.y + bv.y);
  o.z = f2bf((v.z - mu) * rs * gv.z + bv.z);
  o.w = f2bf((v.w - mu) * rs * gv.w + bv.w);
  *(ushort4*)(out + (size_t)row * 1024 + t * 4) = o;
}

// ---------------- GEMM: C[M][N] = A[M][K] * Bt[N][K]^T + bias ----------------
// EPI 0: store bf16; EPI 1: gelu(exact)+store bf16; EPI 2: f32 atomicAdd (+bias when kp==0)
// EPI 3: QKV split — cols<2048 -> Cout (Q|K, row stride 2048); cols>=2048 -> Cout2 as
//        V^T [bh][e][t] (bh = b*16+head, e = col&63, t = row&2047) — feeds attention PV directly.
// 1-D grid of nbx*nby*kparts blocks, XCD-swizzled (grid must be divisible by 8).
// LDS tiles [128 rows][8 chunks of 16B], chunk slot c holds global chunk c ^ (row&7)
// (involution; staged via gload_lds with pre-swizzled SOURCE column, read with same XOR).
template <int EPI>
__global__ __launch_bounds__(256) void k_gemm_bt(const unsigned short* __restrict__ A,
                                                 const unsigned short* __restrict__ Bt,
                                                 const float* __restrict__ bias,
                                                 void* __restrict__ Cout,
                                                 void* __restrict__ Cout2,
                                                 int M, int N, int K,
                                                 int nbx, int nby, int kparts) {
  __shared__ __align__(16) unsigned short As[128 * 64];
  __shared__ __align__(16) unsigned short Bs[128 * 64];
  int tid = threadIdx.x;

  int nwg = nbx * nby * kparts;
  int flat = blockIdx.x;
  int swz = (flat & 7) * (nwg >> 3) + (flat >> 3);   // XCD-contiguous logical id
  int bx = swz % nbx;
  int rest = swz / nbx;
  int by = rest % nby;
  int kp = rest / nby;
  int col0 = bx * 128;
  int row0 = by * 128;
  int kLen = K / kparts;
  int kBeg = kp * kLen;

  int wid = tid >> 6, lane = tid & 63;
  int wr = wid >> 1, wc = wid & 1;
  int lrow = lane & 15;
  int g = lane >> 4;
  int s_row = tid >> 3;                                // dest row within 32-row slab
  int s_scol = ((tid & 7) ^ (s_row & 7)) * 8;          // pre-swizzled global k-chunk

  f32x4 acc[4][4];
  f32x4 zero = {0.f, 0.f, 0.f, 0.f};
  #pragma unroll
  for (int m = 0; m < 4; ++m)
    #pragma unroll
    for (int n = 0; n < 4; ++n) acc[m][n] = zero;

  for (int k0 = kBeg; k0 < kBeg + kLen; k0 += 64) {
    #pragma unroll
    for (int i = 0; i < 4; ++i) {
      int r = i * 32 + s_row;
      gload_lds16(A  + (size_t)(row0 + r) * K + k0 + s_scol, (char*)As + i * 4096 + tid * 16);
      gload_lds16(Bt + (size_t)(col0 + r) * K + k0 + s_scol, (char*)Bs + i * 4096 + tid * 16);
    }
    __syncthreads();
    bf16x8 af[4][2], bf[4][2];
    #pragma unroll
    for (int m = 0; m < 4; ++m) {
      int ra = wr * 64 + m * 16 + lrow;
      #pragma unroll
      for (int kk = 0; kk < 2; ++kk) {
        int byteoff = ra * 128 + (((kk * 4 + g) ^ (lrow & 7)) << 4);
        af[m][kk] = *(const bf16x8*)((const char*)As + byteoff);
      }
    }
    #pragma unroll
    for (int n = 0; n < 4; ++n) {
      int rb = wc * 64 + n * 16 + lrow;
      #pragma unroll
      for (int kk = 0; kk < 2; ++kk) {
        int byteoff = rb * 128 + (((kk * 4 + g) ^ (lrow & 7)) << 4);
        bf[n][kk] = *(const bf16x8*)((const char*)Bs + byteoff);
      }
    }
    #pragma unroll
    for (int m = 0; m < 4; ++m)
      #pragma unroll
      for (int n = 0; n < 4; ++n)
        #pragma unroll
        for (int kk = 0; kk < 2; ++kk)
          acc[m][n] = __builtin_amdgcn_mfma_f32_16x16x32_bf16(af[m][kk], bf[n][kk], acc[m][n], 0, 0, 0);
    __syncthreads();
  }

  int rbase = row0 + wr * 64 + g * 4;
  int cbase = col0 + wc * 64 + lrow;
  #pragma unroll
  for (int m = 0; m < 4; ++m) {
    #pragma unroll
    for (int n = 0; n < 4; ++n) {
      int col = cbase + n * 16;
      float bia = bias[col];
      #pragma unroll
      for (int j = 0; j < 4; ++j) {
        int row = rbase + m * 16 + j;
        float v = acc[m][n][j];
        if constexpr (EPI == 0) {
          ((unsigned short*)Cout)[(size_t)row * N + col] = f2bf(v + bia);
        } else if constexpr (EPI == 1) {
          float u = v + bia;
          float gel = 0.5f * u * (1.0f + erff(u * 0.70710678118f));
          ((unsigned short*)Cout)[(size_t)row * N + col] = f2bf(gel);
        } else if constexpr (EPI == 2) {
          float u = v + (kp == 0 ? bia : 0.0f);
          atomicAdd((float*)Cout + (size_t)row * N + col, u);
        } else {  // EPI == 3: QKV split write
          unsigned short bfv = f2bf(v + bia);
          if (col < 2048) {
            ((unsigned short*)Cout)[(size_t)row * 2048 + col] = bfv;
          } else {
            int e = col & 63;
            int head = (col >> 6) & 15;
            int bb = row >> 11;
            int t = row & 2047;
            ((unsigned short*)Cout2)[(((size_t)bb * 16 + head) * 64 + e) * 2048 + t] = bfv;
          }
        }
      }
    }
  }
}

// ---------------- fused causal flash attention + residual ----------------
// qkv: bf16 [4096][2048] (Q|K per head concat); vT: bf16 [32 bh][64 e][2048 t];
// x: f32 [4096][1024]; out = x + attn
// Grid: 512 blocks = 32 (b*h) x 16 q-tile pairs (p, 31-p) -> 33 KV-tile iters each.
// LDS layouts XOR-chunk-swizzled (16B chunks, row stride 128B):
//   Ks[buf][row t][chunk c]: holds global d-chunk c ^ (t&7)   (gload_lds, pre-swizzled src)
//   Vs[buf][row e][chunk c]: holds global t-chunk c ^ (e&7)   (gload_lds, pre-swizzled src)
//   Pl[wave][row q][chunk c]: holds t-chunk c ^ (q&7)
__global__ __launch_bounds__(256) void k_flash_attn(const unsigned short* __restrict__ qkv,
                                                    const unsigned short* __restrict__ vT,
                                                    const float* __restrict__ x,
                                                    float* __restrict__ out) {
  int blk = blockIdx.x;
  int pairIdx = blk & 15;
  int bh = blk >> 4;
  int b = bh >> 4, h = bh & 15;
  const int LDQ = 2048;
  int tb = b * 2048;
  int qcol = h * 64, kcol = 1024 + h * 64;
  const unsigned short* vbase = vT + (size_t)bh * 64 * 2048;
  int tid = threadIdx.x, wid = tid >> 6, lane = tid & 63;
  int lrow = lane & 15;
  int g = lane >> 4;
  int kgrp = g * 8;

  __shared__ __align__(16) unsigned short Ks[2][64 * 64];
  __shared__ __align__(16) unsigned short Vs[2][64 * 64];
  __shared__ __align__(16) unsigned short Pl[4][16 * 64];

  // staging coords (gload_lds, linear dest, pre-swizzled source)
  int s_row = tid >> 3;                                  // 0..31 (+32*i)
  int s_scol = ((tid & 7) ^ ((tid >> 3) & 7)) * 8;       // swizzled global chunk

  unsigned short* myP = &Pl[wid][0];
  f32x4 zero = {0.f, 0.f, 0.f, 0.f};

  for (int half = 0; half < 2; ++half) {
    int qt = (half == 0) ? pairIdx : 31 - pairIdx;
    int q0 = qt * 64;
    int nkv = qt + 1;

    // Q fragments: wave owns rows q0 + wid*16 .. +15
    bf16x8 aq[2];
    #pragma unroll
    for (int kk = 0; kk < 2; ++kk)
      aq[kk] = *(const bf16x8*)(qkv + (size_t)(tb + q0 + wid * 16 + lrow) * LDQ + qcol + kk * 32 + kgrp);

    f32x4 oacc[4];
    #pragma unroll
    for (int e = 0; e < 4; ++e) oacc[e] = zero;
    float mrun[4], lrun[4];
    #pragma unroll
    for (int r = 0; r < 4; ++r) { mrun[r] = -1e30f; lrun[r] = 0.0f; }

    int cur = 0;

    __syncthreads();  // all waves done reading LDS from previous half before restaging
    // ---- prologue: stage K+V tile 0 into buf 0 ----
    #pragma unroll
    for (int i = 0; i < 2; ++i) {
      gload_lds16(qkv + (size_t)(tb + i * 32 + s_row) * LDQ + kcol + s_scol,
                  (char*)Ks[0] + i * 4096 + tid * 16);
      gload_lds16(vbase + (size_t)(i * 32 + s_row) * 2048 + s_scol,
                  (char*)Vs[0] + i * 4096 + tid * 16);
    }

    for (int j = 0; j < nkv; ++j) {
      __syncthreads();   // staging of buf[cur] complete; prior reads of buf[cur^1] done
      int nxt = cur ^ 1;
      if (j + 1 < nkv) {
        // issue next K+V tiles (async to LDS) EARLY — overlap with this tile's compute
        #pragma unroll
        for (int i = 0; i < 2; ++i) {
          gload_lds16(qkv + (size_t)(tb + (j + 1) * 64 + i * 32 + s_row) * LDQ + kcol + s_scol,
                      (char*)Ks[nxt] + i * 4096 + tid * 16);
          gload_lds16(vbase + (size_t)(i * 32 + s_row) * 2048 + (j + 1) * 64 + s_scol,
                      (char*)Vs[nxt] + i * 4096 + tid * 16);
        }
      }

      // ---- S = Q K^T (16 q-rows x 64 keys per wave) ----
      f32x4 sacc[4];
      #pragma unroll
      for (int n = 0; n < 4; ++n) sacc[n] = zero;
      __builtin_amdgcn_s_setprio(1);
      #pragma unroll
      for (int n = 0; n < 4; ++n) {
        int trow = n * 16 + lrow;
        #pragma unroll
        for (int kk = 0; kk < 2; ++kk) {
          int byteoff = trow * 128 + (((kk * 4 + g) ^ (trow & 7)) << 4);
          bf16x8 bk = *(const bf16x8*)((const char*)Ks[cur] + byteoff);
          sacc[n] = __builtin_amdgcn_mfma_f32_16x16x32_bf16(aq[kk], bk, sacc[n], 0, 0, 0);
        }
      }
      __builtin_amdgcn_s_setprio(0);

      // ---- online softmax ----
      bool diag = (j == qt);
      float pv[4][4];
      #pragma unroll
      for (int r = 0; r < 4; ++r) {
        int sg = q0 + wid * 16 + g * 4 + r;          // global query index
        float mx = -1e30f;
        #pragma unroll
        for (int n = 0; n < 4; ++n) {
          float sv = sacc[n][r] * 0.125f;
          int tg = j * 64 + n * 16 + lrow;           // global key index
          if (diag && tg > sg) sv = -1e30f;
          pv[r][n] = sv;
          mx = fmaxf(mx, sv);
        }
        #pragma unroll
        for (int off = 1; off < 16; off <<= 1) mx = fmaxf(mx, __shfl_xor(mx, off, 64));
        float mnew = fmaxf(mrun[r], mx);
        float esc = __expf(mrun[r] - mnew);
        float rsum = 0.f;
        #pragma unroll
        for (int n = 0; n < 4; ++n) {
          float p = __expf(pv[r][n] - mnew);
          pv[r][n] = p;
          rsum += p;
        }
        #pragma unroll
        for (int off = 1; off < 16; off <<= 1) rsum += __shfl_xor(rsum, off, 64);
        lrun[r] = lrun[r] * esc + rsum;
        mrun[r] = mnew;
        #pragma unroll
        for (int e = 0; e < 4; ++e) oacc[e][r] *= esc;
      }

      // ---- write P (wave-private, swizzled) ----
      #pragma unroll
      for (int r = 0; r < 4; ++r) {
        int q = g * 4 + r;
        #pragma unroll
        for (int n = 0; n < 4; ++n) {
          int t = n * 16 + lrow;
          int byteoff = q * 128 + ((((t >> 3) ^ (q & 7)) & 7) << 4) + (t & 7) * 2;
          *(unsigned short*)((char*)myP + byteoff) = f2bf(pv[r][n]);
        }
      }

      // ---- O += P V (in-wave LDS dependency; compiler inserts lgkmcnt) ----
      __builtin_amdgcn_s_setprio(1);
      #pragma unroll
      for (int kk = 0; kk < 2; ++kk) {
        int pbyte = lrow * 128 + (((kk * 4 + g) ^ (lrow & 7)) << 4);
        bf16x8 ap = *(const bf16x8*)((const char*)myP + pbyte);
        #pragma unroll
        for (int e = 0; e < 4; ++e) {
          int erow = e * 16 + lrow;
          int vbyte = erow * 128 + (((kk * 4 + g) ^ (erow & 7)) << 4);
          bf16x8 bv = *(const bf16x8*)((const char*)Vs[cur] + vbyte);
          oacc[e] = __builtin_amdgcn_mfma_f32_16x16x32_bf16(ap, bv, oacc[e], 0, 0, 0);
        }
      }
      __builtin_amdgcn_s_setprio(0);
      cur = nxt;
    }

    // ---- epilogue: out = x + O / l ----
    #pragma unroll
    for (int r = 0; r < 4; ++r) {
      float inv = 1.0f / lrun[r];
      int row = tb + q0 + wid * 16 + g * 4 + r;
      #pragma unroll
      for (int e = 0; e < 4; ++e) {
        size_t idx = (size_t)row * 1024 + h * 64 + e * 16 + lrow;
        out[idx] = x[idx] + oacc[e][r] * inv;
      }
    }
  }
}

// ---------------- launch ----------------
extern "C" void kernel_launch(void* const* d_in, const int* in_sizes, int n_in,
                              void* d_out, int out_size, void* d_ws, size_t ws_size,
                              hipStream_t stream) {
  (void)in_sizes; (void)n_in; (void)out_size; (void)ws_size;
  const float* x    = (const float*)d_in[0];
  const float* Wq   = (const float*)d_in[1];
  const float* bq   = (const float*)d_in[2];
  const float* Wk   = (const float*)d_in[3];
  const float* bk   = (const float*)d_in[4];
  const float* Wv   = (const float*)d_in[5];
  const float* bv   = (const float*)d_in[6];
  const float* ln1g = (const float*)d_in[7];
  const float* ln1b = (const float*)d_in[8];
  const float* ln2g = (const float*)d_in[9];
  const float* ln2b = (const float*)d_in[10];
  const float* W1   = (const float*)d_in[11];
  const float* b1   = (const float*)d_in[12];
  const float* W2   = (const float*)d_in[13];
  const float* b2   = (const float*)d_in[14];
  float* out = (float*)d_out;
  char* ws = (char*)d_ws;

  unsigned short* h1    = (unsigned short*)(ws + 0);          // 8 MiB  [4096][1024] bf16
  unsigned short* wqkvT = (unsigned short*)(ws + 8388608);    // 6 MiB  [3072][1024] bf16
  unsigned short* w1T   = (unsigned short*)(ws + 14680064);   // 8 MiB  [4096][1024] bf16
  unsigned short* w2T   = (unsigned short*)(ws + 23068672);   // 8 MiB  [1024][4096] bf16
  float*          bqkv  = (float*)(ws + 31457280);            // 12 KiB [3072] f32
  unsigned short* qkv   = (unsigned short*)(ws + 33554432);   // 16 MiB [4096][2048] bf16 (Q|K)
  unsigned short* vT    = (unsigned short*)(ws + 50331648);   // 8 MiB  [32][64][2048] bf16 (V^T)
  unsigned short* fbuf  = (unsigned short*)(ws + 33554432);   // 32 MiB [4096][4096] bf16 (overlaps qkv+vT; dead by then)

  dim3 tb(32, 8);
  // Wq/Wk/Wv: [16][1024][64] -> [16][64][1024] concat into wqkvT
  k_transpose<<<dim3(2, 32, 16), tb, 0, stream>>>(Wq, wqkvT,               1024, 64, 1024L * 64, 64L * 1024);
  k_transpose<<<dim3(2, 32, 16), tb, 0, stream>>>(Wk, wqkvT + 1024 * 1024, 1024, 64, 1024L * 64, 64L * 1024);
  k_transpose<<<dim3(2, 32, 16), tb, 0, stream>>>(Wv, wqkvT + 2048 * 1024, 1024, 64, 1024L * 64, 64L * 1024);
  // W1: [1024][4096] -> w1T [4096][1024]
  k_transpose<<<dim3(128, 32, 1), tb, 0, stream>>>(W1, w1T, 1024, 4096, 0, 0);
  // W2: [4096][1024] -> w2T [1024][4096]
  k_transpose<<<dim3(32, 128, 1), tb, 0, stream>>>(W2, w2T, 4096, 1024, 0, 0);
  k_concat_bias<<<12, 256, 0, stream>>>(bq, bk, bv, bqkv);

  // LN1
  k_ln_bf16<<<4096, 256, 0, stream>>>(x, ln1g, ln1b, h1);
  // QKV projection: [4096][1024] x [1024][3072] -> qkv (Q|K) + vT (V^T), XCD-swizzled
  k_gemm_bt<3><<<768, 256, 0, stream>>>(h1, wqkvT, bqkv, qkv, vT, 4096, 3072, 1024, 24, 32, 1);
  // attention + residual: out = x + attn  (512 balanced blocks)
  k_flash_attn<<<512, 256, 0, stream>>>(qkv, vT, x, out);
  // LN2 (reads out)
  k_ln_bf16<<<4096, 256, 0, stream>>>(out, ln2g, ln2b, h1);
  // FFN1 + GELU: [4096][1024] x [1024][4096] -> fbuf bf16 (1024 blocks)
  k_gemm_bt<1><<<1024, 256, 0, stream>>>(h1, w1T, b1, fbuf, nullptr, 4096, 4096, 1024, 32, 32, 1);
  // FFN2: [4096][4096] x [4096][1024] += out (split-K=2, atomic f32 accumulate)
  k_gemm_bt<2><<<512, 256, 0, stream>>>(fbuf, w2T, b2, out, nullptr, 4096, 1024, 4096, 8, 32, 2);
}